// Round 7
// baseline (145.057 us; speedup 1.0000x reference)
//
#include <hip/hip_runtime.h>
#include <cstddef>
#include <cstdint>

typedef __attribute__((ext_vector_type(8))) _Float16 half8;
typedef __attribute__((ext_vector_type(4))) float f32x4;

constexpr int Bsz = 2048, Tsz = 120, Ksz = 128;
constexpr float L2E = 1.44269504088896340736f;  // log2(e)
constexpr float LN2 = 0.69314718055994530942f;  // ln(2)

__device__ __forceinline__ int expbits(float x) {
  return (int)(__float_as_uint(x) >> 23) - 127;   // floor(log2 x), x > 0
}

// LDS ordering fence (cross-lane visibility within the wave) + scheduler
// pin (rule #18: don't let anything drift across the wait).
#define LDS_FENCE() do {                                      \
    asm volatile("s_waitcnt lgkmcnt(0)" ::: "memory");        \
    __builtin_amdgcn_sched_barrier(0);                        \
  } while (0)

// One wave per 16 batches; all 128 states in-wave: no barriers.
// Linear-space recursion invariant: alpha*log2e = nReg + log2(P).
// Per step: S = E^T·P (MFMA); P' = S * exp(em - Df*ln2); nReg += Df.
// Df = expbits(max_col P_prev) + 8 -- DELAY-FREE normalizer: S is built from
// P_prev, so bounds depend only on current-step emissions (no oscillation):
//   S/2^Df in [0.0023, 1.6],  P' in [0.0023*e^em_min, 1.6*e^em_max] -- f16-safe.
__global__ __launch_bounds__(64, 1) void crf_fwd(
    const float* __restrict__ emis,   // [B,T,K]
    const int* __restrict__ tag,      // [B,T]
    const int* __restrict__ maskg,    // [B,T]
    const float* __restrict__ Tg,     // [K,K]
    float* __restrict__ nll)          // [B]
{
  // P buffer: 16 cols x 32 uint2 (=256B per col). ALL accesses via uint2.
  __shared__ __align__(16) uint2 Pb[16 * 32];
  __shared__ int maskLds[Tsz * 16];             // [t][c]

  const int lane = threadIdx.x & 63;
  const int c = lane & 15, hi = lane >> 4;
  const int b0 = blockIdx.x * 16;
  const int sw2 = (c & 7) << 1;                 // XOR swizzle in uint2 units
  uint2* const prow = Pb + c * 32;

  // stage masks (single wave)
  for (int i = lane; i < Tsz * 16; i += 64) {
    int cc = i & 15, tt = i >> 4;
    maskLds[i] = maskg[(size_t)(b0 + cc) * Tsz + tt];
  }

  const float* ep = emis + (size_t)(b0 + c) * Tsz * Ksz + 4 * hi;

  // t=0 emissions + prefetch t=1,2 (issued before the Ef crunch)
  f32x4 a0[8], emA[8], emB[8];
  #pragma unroll
  for (int q = 0; q < 8; ++q) a0[q] = *(const f32x4*)(ep + 16 * q);
  #pragma unroll
  for (int q = 0; q < 8; ++q) emA[q] = *(const f32x4*)(ep + (size_t)1 * Ksz + 16 * q);
  #pragma unroll
  for (int q = 0; q < 8; ++q) emB[q] = *(const f32x4*)(ep + (size_t)2 * Ksz + 16 * q);

  // E^T A-fragments in registers for the whole kernel:
  // A[row=16q+c][k=32m+8hi+j] = exp(T[k][row])
  half8 Ef[8][4];
  #pragma unroll
  for (int q = 0; q < 8; ++q)
    #pragma unroll
    for (int m = 0; m < 4; ++m) {
      half8 v;
      #pragma unroll
      for (int j = 0; j < 8; ++j)
        v[j] = (_Float16)__expf(Tg[(size_t)(32 * m + 8 * hi + j) * Ksz + 16 * q + c]);
      Ef[q][m] = v;
    }

  // ---- prologue: alpha_0 = emis[:,0,:]; per-col max -> normalizer; write P0
  float mx = -3.0e38f;
  #pragma unroll
  for (int q = 0; q < 8; ++q)
    #pragma unroll
    for (int r = 0; r < 4; ++r) mx = fmaxf(mx, a0[q][r]);
  mx = fmaxf(mx, __shfl_xor(mx, 16, 64));
  mx = fmaxf(mx, __shfl_xor(mx, 32, 64));
  float nReg = mx * L2E;                    // base-2 normalizer (per col)

  f32x4 Pv[8];
  #pragma unroll
  for (int q = 0; q < 8; ++q)
    #pragma unroll
    for (int r = 0; r < 4; ++r)
      Pv[q][r] = __expf(a0[q][r] - mx);     // in (0,1], max = 1 exactly

  float dPend = 8.0f;                       // expbits(maxP0=1) + 8

  #pragma unroll
  for (int q = 0; q < 8; ++q) {
    union { _Float16 h[4]; uint2 u; } pk;
    #pragma unroll
    for (int r = 0; r < 4; ++r) pk.h[r] = (_Float16)Pv[q][r];
    prow[(4 * q + hi) ^ sw2] = pk.u;        // state block 16q+4hi
  }
  LDS_FENCE();

  const f32x4 z = {0.f, 0.f, 0.f, 0.f};

  auto STEP = [&](int t, f32x4 (&em)[8]) {
    // B-fragments: P[k=32m+8hi+j][col c] -- two adjacent uint2 per m
    half8 bf[4];
    #pragma unroll
    for (int m = 0; m < 4; ++m) {
      union { uint2 u2[2]; half8 h; } rb;
      const int idx = (8 * m + 2 * hi) ^ sw2;   // bit0 untouched by sw2
      rb.u2[0] = prow[idx];
      rb.u2[1] = prow[idx + 1];
      bf[m] = rb.h;
    }
    const int mt = maskLds[t * 16 + c];
    const float Df = dPend;

    // scale = exp(em - Df*ln2): independent of S, overlaps MFMA
    f32x4 scale[8];
    #pragma unroll
    for (int q = 0; q < 8; ++q)
      #pragma unroll
      for (int r = 0; r < 4; ++r)
        scale[q][r] = __expf(__fmaf_rn(-Df, LN2, em[q][r]));

    f32x4 acc[8];
    #pragma unroll
    for (int q = 0; q < 8; ++q) {
      acc[q] = __builtin_amdgcn_mfma_f32_16x16x32_f16(Ef[q][0], bf[0], z, 0, 0, 0);
      #pragma unroll
      for (int m = 1; m < 4; ++m)
        acc[q] = __builtin_amdgcn_mfma_f32_16x16x32_f16(Ef[q][m], bf[m], acc[q], 0, 0, 0);
    }

    // prefetch emis[t+2] into the buffer just consumed
    if (t + 2 < Tsz) {
      #pragma unroll
      for (int q = 0; q < 8; ++q)
        em[q] = *(const f32x4*)(ep + (size_t)(t + 2) * Ksz + 16 * q);
    }

    // new P (fast path: all 16 cols unmasked -- wave-uniform branch)
    unsigned long long bal = __ballot(mt > 0);
    if (bal == ~0ull) {
      #pragma unroll
      for (int q = 0; q < 8; ++q)
        #pragma unroll
        for (int r = 0; r < 4; ++r) Pv[q][r] = acc[q][r] * scale[q][r];
    } else {
      const float inv = __expf(-Df * LN2);
      #pragma unroll
      for (int q = 0; q < 8; ++q) {
        union { _Float16 h[4]; uint2 u; } pr;
        pr.u = prow[(4 * q + hi) ^ sw2];
        #pragma unroll
        for (int r = 0; r < 4; ++r) {
          float pn = acc[q][r] * scale[q][r];
          float po = (float)pr.h[r] * inv;
          Pv[q][r] = (mt > 0) ? pn : po;
        }
      }
    }
    nReg += Df;

    // DELAY-FREE normalizer for next step: Df' = expbits(max_col P') + 8.
    // Off the critical path (hidden under next step's ds_read + MFMA).
    float lam = 0.f;
    #pragma unroll
    for (int q = 0; q < 8; ++q)
      #pragma unroll
      for (int r = 0; r < 4; ++r) lam = fmaxf(lam, Pv[q][r]);
    lam = fmaxf(lam, __shfl_xor(lam, 16, 64));
    lam = fmaxf(lam, __shfl_xor(lam, 32, 64));
    dPend = (float)(expbits(lam) + 8);

    // publish P_t
    #pragma unroll
    for (int q = 0; q < 8; ++q) {
      union { _Float16 h[4]; uint2 u; } pk;
      #pragma unroll
      for (int r = 0; r < 4; ++r) pk.h[r] = (_Float16)Pv[q][r];
      prow[(4 * q + hi) ^ sw2] = pk.u;
    }
    LDS_FENCE();   // order publish before next step's reads
  };

  #pragma unroll 1
  for (int t = 1; t <= Tsz - 2; t += 2) {  // steps 1..118
    STEP(t, emA);
    STEP(t + 1, emB);
  }

  // ---- last step t = 119: materialize alpha (base-2 units) with real logs
  f32x4 al[8];
  {
    const int t = Tsz - 1;
    half8 bf[4];
    #pragma unroll
    for (int m = 0; m < 4; ++m) {
      union { uint2 u2[2]; half8 h; } rb;
      const int idx = (8 * m + 2 * hi) ^ sw2;
      rb.u2[0] = prow[idx];
      rb.u2[1] = prow[idx + 1];
      bf[m] = rb.h;
    }
    const int mt = maskLds[t * 16 + c];
    f32x4 acc[8];
    #pragma unroll
    for (int q = 0; q < 8; ++q) {
      acc[q] = __builtin_amdgcn_mfma_f32_16x16x32_f16(Ef[q][0], bf[0], z, 0, 0, 0);
      #pragma unroll
      for (int m = 1; m < 4; ++m)
        acc[q] = __builtin_amdgcn_mfma_f32_16x16x32_f16(Ef[q][m], bf[m], acc[q], 0, 0, 0);
    }
    unsigned long long bal = __ballot(mt > 0);
    if (bal == ~0ull) {
      #pragma unroll
      for (int q = 0; q < 8; ++q)
        #pragma unroll
        for (int r = 0; r < 4; ++r)
          al[q][r] = nReg + (__logf(acc[q][r]) + emA[q][r]) * L2E;
    } else {
      #pragma unroll
      for (int q = 0; q < 8; ++q)
        #pragma unroll
        for (int r = 0; r < 4; ++r) {
          float aN = nReg + (__logf(acc[q][r]) + emA[q][r]) * L2E;
          float aO = nReg + __logf(Pv[q][r]) * L2E;
          al[q][r] = (mt > 0) ? aN : aO;
        }
    }
  }

  // ---- final logsumexp (per col), base-2 internal, natural-log result
  float mg = -3.0e38f;
  #pragma unroll
  for (int q = 0; q < 8; ++q)
    #pragma unroll
    for (int r = 0; r < 4; ++r) mg = fmaxf(mg, al[q][r]);
  mg = fmaxf(mg, __shfl_xor(mg, 16, 64));
  mg = fmaxf(mg, __shfl_xor(mg, 32, 64));
  float psum = 0.f;
  #pragma unroll
  for (int q = 0; q < 8; ++q)
    #pragma unroll
    for (int r = 0; r < 4; ++r) psum += __expf((al[q][r] - mg) * LN2);
  psum += __shfl_xor(psum, 16, 64);
  psum += __shfl_xor(psum, 32, 64);
  const float lognorm = mg * LN2 + __logf(psum);

  // ---- score: lane (c,hi) -> batch c, t-chunk hi (30 steps each)
  {
    const int* tb = tag + (size_t)(b0 + c) * Tsz;
    const float* eb2 = emis + (size_t)(b0 + c) * Tsz * Ksz;
    float sc = 0.f;
    const int t0 = 30 * hi, t1 = t0 + 30;
    int tgp = tb[t0];
    float mp = (float)maskLds[t0 * 16 + c];
    #pragma unroll 1
    for (int t = t0; t < t1; ++t) {
      sc += eb2[(size_t)t * Ksz + tgp] * mp;
      if (t + 1 < Tsz) {
        int tgn = tb[t + 1];
        float mn = (float)maskLds[(t + 1) * 16 + c];
        sc += Tg[(size_t)tgp * Ksz + tgn] * mp * mn;
        tgp = tgn; mp = mn;
      }
    }
    sc += __shfl_xor(sc, 16, 64);
    sc += __shfl_xor(sc, 32, 64);
    if (lane < 16) nll[b0 + c] = lognorm - sc;
  }
}

// deterministic fixed-order mean over B values
__global__ __launch_bounds__(256) void crf_reduce(
    const float* __restrict__ nll, float* __restrict__ out) {
  __shared__ float buf[256];
  float s = 0.f;
  for (int i = threadIdx.x; i < Bsz; i += 256) s += nll[i];
  buf[threadIdx.x] = s;
  __syncthreads();
  #pragma unroll
  for (int off = 128; off > 0; off >>= 1) {
    if (threadIdx.x < off) buf[threadIdx.x] += buf[threadIdx.x + off];
    __syncthreads();
  }
  if (threadIdx.x == 0) out[0] = buf[0] / (float)Bsz;
}

extern "C" void kernel_launch(void* const* d_in, const int* in_sizes, int n_in,
                              void* d_out, int out_size, void* d_ws, size_t ws_size,
                              hipStream_t stream) {
  const float* emissions   = (const float*)d_in[0];
  const int*   tag_ids     = (const int*)d_in[1];
  const int*   mask        = (const int*)d_in[2];
  const float* transitions = (const float*)d_in[3];

  float* nll = (float*)d_ws;  // 2048 floats

  crf_fwd<<<Bsz / 16, 64, 0, stream>>>(emissions, tag_ids, mask, transitions, nll);
  crf_reduce<<<1, 256, 0, stream>>>(nll, (float*)d_out);
}

// Round 8
// 77.128 us; speedup vs baseline: 1.8807x; 1.8807x over previous
//
#include <hip/hip_runtime.h>
#include <cstddef>
#include <cstdint>

typedef __attribute__((ext_vector_type(8))) _Float16 half8;
typedef __attribute__((ext_vector_type(4))) float f32x4;

constexpr int Bsz = 2048, Tsz = 120, Ksz = 128;
constexpr float L2E = 1.44269504088896340736f;  // log2(e)
constexpr float LN2 = 0.69314718055994530942f;  // ln(2)

__device__ __forceinline__ int expbits(float x) {
  return (int)(__float_as_uint(x) >> 23) - 127;   // floor(log2 x), x > 0
}

// drain LDS ops, then block barrier; pin the scheduler so nothing drifts.
#define BAR() do {                                        \
    asm volatile("s_waitcnt lgkmcnt(0)" ::: "memory");    \
    __builtin_amdgcn_s_barrier();                         \
    __builtin_amdgcn_sched_barrier(0);                    \
  } while (0)

// 4 waves x 16 batches per block. Wave w owns states [32w,32w+32).
// Linear-space recursion: alpha*log2e = nReg + log2(P); per step
//   S = E^T . P  (8 chained MFMAs/wave),  P' = S * exp(em - Df*ln2),
//   Df = expbits(max_col P_prev) + 8  (delay-free; exchanged via per-(w,hi)
//   partial maxes in LDS -- NO shuffles, NO log/exp on the S-dependent path).
__global__ __launch_bounds__(256) void crf_fwd(
    const float* __restrict__ emis,   // [B,T,K]
    const int* __restrict__ tag,      // [B,T]
    const int* __restrict__ maskg,    // [B,T]
    const float* __restrict__ Tg,     // [K,K]
    float* __restrict__ nll)          // [B]
{
  __shared__ float Tst[Ksz * Ksz];                  // 64 KB transitions copy
  __shared__ __align__(16) uint2 Pb[2][16 * 32];    // P f16, dbuf, XOR swizzle
  __shared__ __align__(16) float lamp[2][16][20];   // per-(w,hi) partial maxes
  __shared__ int maskLds[Tsz * 16];                 // [t][c]

  const int tid = threadIdx.x;
  const int w = tid >> 6, lane = tid & 63;
  const int c = lane & 15, hi = lane >> 4;
  const int b0 = blockIdx.x * 16;
  const int sw2 = (c & 7) << 1;                     // swizzle in uint2 units
  const int slot = 4 * w + hi;                      // 0..15 partial slot

  // emissions base for (col c, this wave's state slice)
  const int soff = 32 * w + 4 * hi;
  const float* ep = emis + (size_t)(b0 + c) * Tsz * Ksz + soff;

  // issue t=0,1,2 emission loads early
  f32x4 a0[2], emA[2], emB[2];
  a0[0] = *(const f32x4*)(ep);
  a0[1] = *(const f32x4*)(ep + 16);
  emA[0] = *(const f32x4*)(ep + Ksz);
  emA[1] = *(const f32x4*)(ep + Ksz + 16);
  emB[0] = *(const f32x4*)(ep + 2 * Ksz);
  emB[1] = *(const f32x4*)(ep + 2 * Ksz + 16);

  // coalesced stage of transitions + masks
  {
    const f32x4* src = (const f32x4*)Tg;
    f32x4* dst = (f32x4*)Tst;
    #pragma unroll
    for (int k = 0; k < (Ksz * Ksz / 4) / 256; ++k)
      dst[tid + k * 256] = src[tid + k * 256];
  }
  for (int i = tid; i < Tsz * 16; i += 256) {
    int cc = i & 15, tt = i >> 4;
    maskLds[i] = maskg[(size_t)(b0 + cc) * Tsz + tt];
  }
  __syncthreads();

  // E^T A-fragments: A[row=32w+16rti+c][k=32m+8hi+j] = exp(T[k][row])
  half8 Ef[2][4];
  #pragma unroll
  for (int rti = 0; rti < 2; ++rti)
    #pragma unroll
    for (int m = 0; m < 4; ++m) {
      half8 v;
      #pragma unroll
      for (int j = 0; j < 8; ++j)
        v[j] = (_Float16)__expf(Tst[(32 * m + 8 * hi + j) * Ksz + (32 * w + 16 * rti + c)]);
      Ef[rti][m] = v;
    }

  // ---- prologue: cross-wave per-col max of alpha0 via lamp[1] scratch
  {
    float pm = fmaxf(fmaxf(fmaxf(a0[0][0], a0[0][1]), fmaxf(a0[0][2], a0[0][3])),
                     fmaxf(fmaxf(a0[1][0], a0[1][1]), fmaxf(a0[1][2], a0[1][3])));
    lamp[1][c][slot] = pm;
  }
  BAR();
  float nReg;
  f32x4 Pv[2];
  {
    const float* lr = &lamp[1][c][0];
    f32x4 l0 = *(const f32x4*)(lr), l1 = *(const f32x4*)(lr + 4);
    f32x4 l2 = *(const f32x4*)(lr + 8), l3 = *(const f32x4*)(lr + 12);
    f32x4 mm;
    #pragma unroll
    for (int r = 0; r < 4; ++r) mm[r] = fmaxf(fmaxf(l0[r], l1[r]), fmaxf(l2[r], l3[r]));
    float mx = fmaxf(fmaxf(mm[0], mm[1]), fmaxf(mm[2], mm[3]));
    nReg = mx * L2E;
    #pragma unroll
    for (int rti = 0; rti < 2; ++rti)
      #pragma unroll
      for (int r = 0; r < 4; ++r) Pv[rti][r] = __expf(a0[rti][r] - mx);
  }

  // publish Pv into buffer wr (+ per-slot partial max)
  auto publish = [&](int wr) {
    float pl = 0.f;
    #pragma unroll
    for (int rti = 0; rti < 2; ++rti) {
      union { _Float16 h[4]; uint2 u; } pk;
      #pragma unroll
      for (int r = 0; r < 4; ++r) {
        pk.h[r] = (_Float16)Pv[rti][r];
        pl = fmaxf(pl, Pv[rti][r]);
      }
      Pb[wr][c * 32 + ((8 * w + 4 * rti + hi) ^ sw2)] = pk.u;
    }
    lamp[wr][c][slot] = pl;
  };

  publish(0);
  BAR();

  const f32x4 z = {0.f, 0.f, 0.f, 0.f};

  auto STEP = [&](int t, f32x4 (&em)[2]) {
    const int rd = (t - 1) & 1, wr = t & 1;
    const uint2* prowR = &Pb[rd][c * 32];
    // B-fragments: P[k=32m+8hi+j][col c]
    half8 bf[4];
    #pragma unroll
    for (int m = 0; m < 4; ++m) {
      union { uint2 u2[2]; half8 h; } rb;
      const int idx = (8 * m + 2 * hi) ^ sw2;   // bit0 untouched by sw2
      rb.u2[0] = prowR[idx];
      rb.u2[1] = prowR[idx + 1];
      bf[m] = rb.h;
    }
    // Df from 16 partial maxes (reads pipeline with bf reads; no shuffles)
    const float* lr = &lamp[rd][c][0];
    f32x4 l0 = *(const f32x4*)(lr), l1 = *(const f32x4*)(lr + 4);
    f32x4 l2 = *(const f32x4*)(lr + 8), l3 = *(const f32x4*)(lr + 12);
    f32x4 mm;
    #pragma unroll
    for (int r = 0; r < 4; ++r) mm[r] = fmaxf(fmaxf(l0[r], l1[r]), fmaxf(l2[r], l3[r]));
    const float lam = fmaxf(fmaxf(mm[0], mm[1]), fmaxf(mm[2], mm[3]));
    const float Df = (float)(expbits(lam) + 8);
    const int mt = maskLds[t * 16 + c];

    // scale = exp(em - Df*ln2): independent of S, overlaps the MFMAs
    f32x4 scale[2];
    #pragma unroll
    for (int rti = 0; rti < 2; ++rti)
      #pragma unroll
      for (int r = 0; r < 4; ++r)
        scale[rti][r] = __expf(__fmaf_rn(-Df, LN2, em[rti][r]));

    f32x4 acc[2];
    #pragma unroll
    for (int rti = 0; rti < 2; ++rti) {
      acc[rti] = __builtin_amdgcn_mfma_f32_16x16x32_f16(Ef[rti][0], bf[0], z, 0, 0, 0);
      #pragma unroll
      for (int m = 1; m < 4; ++m)
        acc[rti] = __builtin_amdgcn_mfma_f32_16x16x32_f16(Ef[rti][m], bf[m], acc[rti], 0, 0, 0);
    }

    // prefetch emis[t+2] into the buffer just consumed
    if (t + 2 < Tsz) {
      em[0] = *(const f32x4*)(ep + (size_t)(t + 2) * Ksz);
      em[1] = *(const f32x4*)(ep + (size_t)(t + 2) * Ksz + 16);
    }

    // new P (fast path: all 16 cols unmasked -- wave-uniform)
    unsigned long long bal = __ballot(mt > 0);
    if (bal == ~0ull) {
      #pragma unroll
      for (int rti = 0; rti < 2; ++rti)
        #pragma unroll
        for (int r = 0; r < 4; ++r) Pv[rti][r] = acc[rti][r] * scale[rti][r];
    } else {
      const float inv = __expf(-Df * LN2);
      #pragma unroll
      for (int rti = 0; rti < 2; ++rti)
        #pragma unroll
        for (int r = 0; r < 4; ++r) {
          float pn = acc[rti][r] * scale[rti][r];
          float po = Pv[rti][r] * inv;
          Pv[rti][r] = (mt > 0) ? pn : po;
        }
    }
    nReg += Df;

    publish(wr);
    BAR();
  };

  #pragma unroll 1
  for (int t = 1; t <= Tsz - 3; t += 2) {   // (1,2)...(117,118)
    STEP(t, emA);
    STEP(t + 1, emB);
  }
  STEP(Tsz - 1, emA);                       // t = 119

  // ---- final: alpha*log2e = nReg + log2(Pv). logsumexp per col needs only
  // the plain sum of P (shared normalizer): no max pass.
  {
    float ss = ((Pv[0][0] + Pv[0][1]) + (Pv[0][2] + Pv[0][3]))
             + ((Pv[1][0] + Pv[1][1]) + (Pv[1][2] + Pv[1][3]));
    lamp[1][c][slot] = ss;   // reuse buffer (last wr was 1; safe after BAR)
  }
  BAR();
  float lognorm;
  {
    const float* lr = &lamp[1][c][0];
    f32x4 l0 = *(const f32x4*)(lr), l1 = *(const f32x4*)(lr + 4);
    f32x4 l2 = *(const f32x4*)(lr + 8), l3 = *(const f32x4*)(lr + 12);
    float tot = (((l0[0] + l0[1]) + (l0[2] + l0[3]))
              + ((l1[0] + l1[1]) + (l1[2] + l1[3])))
              + (((l2[0] + l2[1]) + (l2[2] + l2[3]))
              + ((l3[0] + l3[1]) + (l3[2] + l3[3])));
    lognorm = nReg * LN2 + __logf(tot);
  }

  // ---- score: lane (w,hi,c) -> batch c, t-chunk [8*slot, 8*slot+8)
  {
    const int* tb = tag + (size_t)(b0 + c) * Tsz;
    const float* eb2 = emis + (size_t)(b0 + c) * Tsz * Ksz;
    float sc = 0.f;
    const int t0 = 8 * slot;
    const int t1 = (t0 + 8 < Tsz) ? t0 + 8 : Tsz;
    #pragma unroll 1
    for (int t = t0; t < t1; ++t) {
      int tg0 = tb[t];
      float m0 = (float)maskLds[t * 16 + c];
      sc += eb2[(size_t)t * Ksz + tg0] * m0;
      if (t + 1 < Tsz) {
        int tg1 = tb[t + 1];
        sc += Tst[tg0 * Ksz + tg1] * m0 * (float)maskLds[(t + 1) * 16 + c];
      }
    }
    float* scb = (float*)&Pb[0][0];    // reuse as [c][16]
    scb[c * 16 + slot] = sc;
    BAR();
    if (tid < 16) {                    // w=0, hi=0, c=tid
      const float* sr = &scb[c * 16];
      float s2 = 0.f;
      #pragma unroll
      for (int s = 0; s < 16; ++s) s2 += sr[s];
      nll[b0 + c] = lognorm - s2;
    }
  }
}

// deterministic fixed-order mean over B values
__global__ __launch_bounds__(256) void crf_reduce(
    const float* __restrict__ nll, float* __restrict__ out) {
  __shared__ float buf[256];
  float s = 0.f;
  for (int i = threadIdx.x; i < Bsz; i += 256) s += nll[i];
  buf[threadIdx.x] = s;
  __syncthreads();
  #pragma unroll
  for (int off = 128; off > 0; off >>= 1) {
    if (threadIdx.x < off) buf[threadIdx.x] += buf[threadIdx.x + off];
    __syncthreads();
  }
  if (threadIdx.x == 0) out[0] = buf[0] / (float)Bsz;
}

extern "C" void kernel_launch(void* const* d_in, const int* in_sizes, int n_in,
                              void* d_out, int out_size, void* d_ws, size_t ws_size,
                              hipStream_t stream) {
  const float* emissions   = (const float*)d_in[0];
  const int*   tag_ids     = (const int*)d_in[1];
  const int*   mask        = (const int*)d_in[2];
  const float* transitions = (const float*)d_in[3];

  float* nll = (float*)d_ws;  // 2048 floats

  crf_fwd<<<Bsz / 16, 256, 0, stream>>>(emissions, tag_ids, mask, transitions, nll);
  crf_reduce<<<1, 256, 0, stream>>>(nll, (float*)d_out);
}